// Round 1
// baseline (408.548 us; speedup 1.0000x reference)
//
#include <hip/hip_runtime.h>
#include <hip/hip_bf16.h>
#include <stdint.h>

// EvolvedLoopLinear = dense linear: out[b,j] = sum_i x[b,i]*W[j,i] + b[j]
// M=8192 (batch), N=4096 (out), K=4096 (in). fp32 in/out; bf16 MFMA compute
// (threshold is the bf16 floor). Structure: m97 ladder step 3 (128x128 tile,
// BK=32, global_load_lds width=16, 16x16x32 bf16 MFMA, XCD swizzle).

typedef __bf16 bf16_t;
typedef __bf16 bf16x8 __attribute__((ext_vector_type(8)));
typedef float  f32x4  __attribute__((ext_vector_type(4)));

#define M_DIM 8192
#define N_DIM 4096
#define K_DIM 4096

// global -> LDS direct copy, 16 bytes per lane. LDS dest is wave-uniform
// base + lane*16 (m104/m108); global src is per-lane.
#define GLD16(gp, lp) __builtin_amdgcn_global_load_lds(                    \
    (const __attribute__((address_space(1))) void*)(gp),                   \
    (__attribute__((address_space(3))) void*)(lp), 16, 0, 0)

// ---------------- fp32 -> bf16 convert (vectorized, grid-stride) -----------
__global__ void __launch_bounds__(256) cvt_f32_bf16(
    const float* __restrict__ in, bf16_t* __restrict__ out, long n8)
{
    long i0 = (long)blockIdx.x * blockDim.x + threadIdx.x;
    long stride = (long)gridDim.x * blockDim.x;
    for (long i = i0; i < n8; i += stride) {
        const float4* p = (const float4*)(in + i * 8);
        float4 a = p[0];
        float4 b = p[1];
        bf16x8 o;
        o[0] = (bf16_t)a.x; o[1] = (bf16_t)a.y; o[2] = (bf16_t)a.z; o[3] = (bf16_t)a.w;
        o[4] = (bf16_t)b.x; o[5] = (bf16_t)b.y; o[6] = (bf16_t)b.z; o[7] = (bf16_t)b.w;
        *(bf16x8*)(out + i * 8) = o;
    }
}

// ---------------- bf16 MFMA GEMM, both operands row-major [*, K] -----------
// A = Xbf [M][K], B = Wbf [N][K]; C[m][n] = sum_k A[m][k]*B[n][k] + bias[n]
__global__ void __launch_bounds__(256) gemm_bf16_bt(
    const bf16_t* __restrict__ A, const bf16_t* __restrict__ B,
    const float* __restrict__ bias, float* __restrict__ C)
{
    __shared__ bf16_t sA[128 * 32];   // 8 KB, linear (global_load_lds needs linear)
    __shared__ bf16_t sB[128 * 32];   // 8 KB

    // XCD-aware swizzle (gridDim.x = 2048, divisible by 8 -> simple form OK)
    const int nwg = gridDim.x;
    const int bid = blockIdx.x;
    const int cpx = nwg >> 3;
    const int swz = (bid & 7) * cpx + (bid >> 3);
    const int NBN = N_DIM / 128;          // 32
    const int bm = swz / NBN;
    const int bn = swz % NBN;
    const long blockM = (long)bm * 128;
    const long blockN = (long)bn * 128;

    const int t    = threadIdx.x;
    const int lane = t & 63;
    const int wid  = t >> 6;              // 4 waves
    const int wr   = wid >> 1;            // 2x2 wave grid, each wave 64x64
    const int wc   = wid & 1;
    const int l15  = lane & 15;
    const int lk   = lane >> 4;

    // staging: tile is 128 rows x 32 cols bf16 = 8192 B; 2 issues of
    // 256 threads x 16 B each. thread t covers row t/4 (+64 on issue 1),
    // k-chunk (t&3)*8.
    const bf16_t* gA = A + (blockM + (t >> 2)) * (long)K_DIM + ((t & 3) * 8);
    const bf16_t* gB = B + (blockN + (t >> 2)) * (long)K_DIM + ((t & 3) * 8);
    bf16_t* lA = &sA[wid * 512];          // wave-uniform: wid*1024 bytes
    bf16_t* lB = &sB[wid * 512];

    // fragment LDS element offsets (A: row = l&15, k0 = (l>>4)*8; B symmetric)
    int aOff[4], bOff[4];
#pragma unroll
    for (int m = 0; m < 4; ++m) aOff[m] = (wr * 64 + m * 16 + l15) * 32 + lk * 8;
#pragma unroll
    for (int n = 0; n < 4; ++n) bOff[n] = (wc * 64 + n * 16 + l15) * 32 + lk * 8;

    f32x4 acc[4][4] = {};

    for (int kt = 0; kt < K_DIM; kt += 32) {
        GLD16(gA + kt,                  lA);
        GLD16(gA + kt + 64L * K_DIM,    lA + 2048);
        GLD16(gB + kt,                  lB);
        GLD16(gB + kt + 64L * K_DIM,    lB + 2048);
        __syncthreads();   // compiler emits vmcnt(0) drain before s_barrier

        bf16x8 af[4], bfr[4];
#pragma unroll
        for (int m = 0; m < 4; ++m) af[m]  = *(const bf16x8*)&sA[aOff[m]];
#pragma unroll
        for (int n = 0; n < 4; ++n) bfr[n] = *(const bf16x8*)&sB[bOff[n]];
#pragma unroll
        for (int m = 0; m < 4; ++m)
#pragma unroll
            for (int n = 0; n < 4; ++n)
                acc[m][n] = __builtin_amdgcn_mfma_f32_16x16x32_bf16(
                    af[m], bfr[n], acc[m][n], 0, 0, 0);
        __syncthreads();
    }

    // epilogue: C/D layout col = lane&15, row = (lane>>4)*4 + j  (m89)
    float bv[4];
    long  coln[4];
#pragma unroll
    for (int n = 0; n < 4; ++n) {
        coln[n] = blockN + wc * 64 + n * 16 + l15;
        bv[n]   = bias[coln[n]];
    }
#pragma unroll
    for (int m = 0; m < 4; ++m) {
        long row0 = blockM + wr * 64 + m * 16 + lk * 4;
#pragma unroll
        for (int n = 0; n < 4; ++n) {
#pragma unroll
            for (int j = 0; j < 4; ++j) {
                C[(row0 + j) * (long)N_DIM + coln[n]] = acc[m][n][j] + bv[n];
            }
        }
    }
}

// ---------------- fp32 fallback (only if ws too small) ---------------------
__global__ void __launch_bounds__(256) gemm_f32_fallback(
    const float* __restrict__ A, const float* __restrict__ W,
    const float* __restrict__ bias, float* __restrict__ C)
{
    __shared__ float sA[64][17];
    __shared__ float sB[64][17];
    const int bm = blockIdx.y, bn = blockIdx.x;
    const int t = threadIdx.x;
    const int tx = t & 15, ty = t >> 4;
    const long row0 = (long)bm * 64, col0 = (long)bn * 64;
    float acc[4][4] = {};
    for (int kt = 0; kt < K_DIM; kt += 16) {
        const int r = t >> 2, c = (t & 3) * 4;
        float4 a4 = *(const float4*)&A[(row0 + r) * K_DIM + kt + c];
        float4 b4 = *(const float4*)&W[(col0 + r) * K_DIM + kt + c];
        sA[r][c] = a4.x; sA[r][c + 1] = a4.y; sA[r][c + 2] = a4.z; sA[r][c + 3] = a4.w;
        sB[r][c] = b4.x; sB[r][c + 1] = b4.y; sB[r][c + 2] = b4.z; sB[r][c + 3] = b4.w;
        __syncthreads();
#pragma unroll
        for (int kk = 0; kk < 16; ++kk) {
            float av[4], bv[4];
#pragma unroll
            for (int i = 0; i < 4; ++i) av[i] = sA[ty * 4 + i][kk];
#pragma unroll
            for (int j = 0; j < 4; ++j) bv[j] = sB[tx * 4 + j][kk];
#pragma unroll
            for (int i = 0; i < 4; ++i)
#pragma unroll
                for (int j = 0; j < 4; ++j) acc[i][j] += av[i] * bv[j];
        }
        __syncthreads();
    }
#pragma unroll
    for (int i = 0; i < 4; ++i)
#pragma unroll
        for (int j = 0; j < 4; ++j)
            C[(row0 + ty * 4 + i) * N_DIM + col0 + tx * 4 + j] =
                acc[i][j] + bias[col0 + tx * 4 + j];
}

extern "C" void kernel_launch(void* const* d_in, const int* in_sizes, int n_in,
                              void* d_out, int out_size, void* d_ws, size_t ws_size,
                              hipStream_t stream)
{
    const float* x = (const float*)d_in[0];   // [8192, 4096]
    const float* W = (const float*)d_in[1];   // [4096, 4096]
    const float* b = (const float*)d_in[2];   // [4096]
    float* out = (float*)d_out;               // [8192, 4096] fp32

    const long xe = (long)M_DIM * K_DIM;      // 33,554,432
    const long we = (long)N_DIM * K_DIM;      // 16,777,216
    const size_t need = (size_t)(xe + we) * sizeof(bf16_t);  // ~96 MiB

    if (ws_size >= need) {
        bf16_t* xb = (bf16_t*)d_ws;
        bf16_t* wb = xb + xe;
        cvt_f32_bf16<<<2048, 256, 0, stream>>>(x, xb, xe / 8);
        cvt_f32_bf16<<<1024, 256, 0, stream>>>(W, wb, we / 8);
        gemm_bf16_bt<<<(M_DIM / 128) * (N_DIM / 128), 256, 0, stream>>>(xb, wb, b, out);
    } else {
        dim3 grid(N_DIM / 64, M_DIM / 64);
        gemm_f32_fallback<<<grid, 256, 0, stream>>>(x, W, b, out);
    }
}

// Round 4
// 296.624 us; speedup vs baseline: 1.3773x; 1.3773x over previous
//
#include <hip/hip_runtime.h>
#include <hip/hip_bf16.h>
#include <stdint.h>

// EvolvedLoopLinear: out[b,j] = sum_i x[b,i]*W[j,i] + b[j]
// M=8192, N=4096, K=4096. fp32 in/out, bf16 MFMA compute.
// Round 4: round-2's 256x256 BK=64 4-quadrant-phase schedule, with the
// prologue issue-order race FIXED: compiler fences between stage groups so
// counted vmcnt(8) drains exactly the intended (oldest) tile's loads.
// T1 XCD swizzle + T2 XOR chunk swizzle + T4 counted vmcnt + T5 setprio.

typedef __bf16 bf16_t;
typedef __bf16 bf16x8 __attribute__((ext_vector_type(8)));
typedef float  f32x4  __attribute__((ext_vector_type(4)));

#define M_DIM 8192
#define N_DIM 4096
#define K_DIM 4096
#define NT    (K_DIM / 64)   // 64 K-tiles of BK=64

#define GLD16(gp, lp) __builtin_amdgcn_global_load_lds(                    \
    (const __attribute__((address_space(1))) void*)(gp),                   \
    (__attribute__((address_space(3))) void*)(lp), 16, 0, 0)

#define MFMA(a, b, c) __builtin_amdgcn_mfma_f32_16x16x32_bf16((a), (b), (c), 0, 0, 0)

// compiler-level memory fence: pins issue ORDER of gld_lds groups (the
// intrinsic is argmem-only; provably-disjoint calls are otherwise
// reorderable, which broke the prologue's vmcnt counting in rounds 2-3)
#define FENCE() asm volatile("" ::: "memory")

// ---------------- fp32 -> bf16 convert (vectorized, grid-stride) -----------
__global__ void __launch_bounds__(256) cvt_f32_bf16(
    const float* __restrict__ in, bf16_t* __restrict__ out, long n8)
{
    long i0 = (long)blockIdx.x * blockDim.x + threadIdx.x;
    long stride = (long)gridDim.x * blockDim.x;
    for (long i = i0; i < n8; i += stride) {
        const float4* p = (const float4*)(in + i * 8);
        float4 a = p[0];
        float4 b = p[1];
        bf16x8 o;
        o[0] = (bf16_t)a.x; o[1] = (bf16_t)a.y; o[2] = (bf16_t)a.z; o[3] = (bf16_t)a.w;
        o[4] = (bf16_t)b.x; o[5] = (bf16_t)b.y; o[6] = (bf16_t)b.z; o[7] = (bf16_t)b.w;
        *(bf16x8*)(out + i * 8) = o;
    }
}

// ---------------- 256x256 4-phase bf16 GEMM (A,B row-major [*,K]) ----------
__global__ void __launch_bounds__(512, 1) gemm_256_8ph(
    const bf16_t* __restrict__ A, const bf16_t* __restrict__ B,
    const float* __restrict__ bias, float* __restrict__ C)
{
    // [buf 0/1][ A: 256x64 (16384 el) | B: 256x64 (16384 el) ] = 128 KiB
    __shared__ bf16_t sm[2 * 32768];

    // XCD-aware bijective swizzle (gridDim = 512, divisible by 8)
    const int nwg = gridDim.x;
    const int bid = blockIdx.x;
    const int cpx = nwg >> 3;
    const int swz = (bid & 7) * cpx + (bid >> 3);
    const int NBN = N_DIM / 256;                       // 16
    const long blockM = (long)(swz / NBN) * 256;
    const long blockN = (long)(swz % NBN) * 256;

    const int t    = threadIdx.x;
    const int lane = t & 63;
    const int wid  = t >> 6;        // 8 waves: 2 (M) x 4 (N)
    const int wr   = wid >> 2;      // 0..1 -> 128 rows each
    const int wc   = wid & 3;       // 0..3 -> 64 cols each
    const int l15  = lane & 15;
    const int lk   = lane >> 4;     // 0..3

    // staging: LDS dest linear (t*16B); global src carries inverse chunk
    // swizzle c_global = c_lds ^ (row&7). row = t>>3 (+64 per load), 8
    // 16B-chunks per 64-el row.
    const int cg   = (t & 7) ^ ((t >> 3) & 7);
    const bf16_t* gA = A + (blockM + (t >> 3)) * (long)K_DIM + cg * 8;
    const bf16_t* gB = B + (blockN + (t >> 3)) * (long)K_DIM + cg * 8;
    const int dstT = t * 8;         // element offset; 16 B per thread

    // read side: fragment row = base16 + l15 -> swizzle = l15&7; lane wants
    // global chunk kk*4+lk -> LDS slot (kk*4+lk)^swzr
    const int swzr = l15 & 7;
    const int cOff0 = ((0 * 4 + lk) ^ swzr) << 3;
    const int cOff1 = ((1 * 4 + lk) ^ swzr) << 3;
    const int rowA = (wr * 128 + l15) * 64;
    const int rowB = (wc * 64  + l15) * 64;

    f32x4 acc[8][4] = {};

#define STAGE_A(q, tk) do {                                                \
    const bf16_t* _g = gA + (long)(tk) * 64;                               \
    bf16_t* _l = (bf16_t*)sm + (q) * 32768 + dstT;                         \
    GLD16(_g,                _l);                                          \
    GLD16(_g +  64L * K_DIM, _l + 4096);                                   \
    GLD16(_g + 128L * K_DIM, _l + 8192);                                   \
    GLD16(_g + 192L * K_DIM, _l + 12288); } while (0)

#define STAGE_B(q, tk) do {                                                \
    const bf16_t* _g = gB + (long)(tk) * 64;                               \
    bf16_t* _l = (bf16_t*)sm + (q) * 32768 + 16384 + dstT;                 \
    GLD16(_g,                _l);                                          \
    GLD16(_g +  64L * K_DIM, _l + 4096);                                   \
    GLD16(_g + 128L * K_DIM, _l + 8192);                                   \
    GLD16(_g + 192L * K_DIM, _l + 12288); } while (0)

    // prologue: tile0 -> buf0 (8 loads), FENCE, tile1 -> buf1 (8 loads).
    // The fences pin issue order so vmcnt(8) == "tile0 landed".
    STAGE_B(0, 0); STAGE_A(0, 0);
    FENCE();
    STAGE_B(1, 1); STAGE_A(1, 1);
    FENCE();
    asm volatile("s_waitcnt vmcnt(8)" ::: "memory");
    __builtin_amdgcn_sched_barrier(0);
    __builtin_amdgcn_s_barrier();
    FENCE();

    bf16x8 a0[4][2], a1[4][2], b0[2][2], b1[2][2];

    for (int tk = 0; tk < NT; ++tk) {
        const int q = tk & 1;
        const bf16_t* sA = (const bf16_t*)sm + q * 32768;
        const bf16_t* sB = sA + 16384;

        // ===== phase 1: read A m0-3 (8) + B n0-1 (4); MFMA quadrant 0 =====
#pragma unroll
        for (int m = 0; m < 4; ++m) {
            a0[m][0] = *(const bf16x8*)(sA + rowA + m * 1024 + cOff0);
            a0[m][1] = *(const bf16x8*)(sA + rowA + m * 1024 + cOff1);
        }
#pragma unroll
        for (int n = 0; n < 2; ++n) {
            b0[n][0] = *(const bf16x8*)(sB + rowB + n * 1024 + cOff0);
            b0[n][1] = *(const bf16x8*)(sB + rowB + n * 1024 + cOff1);
        }
        __builtin_amdgcn_s_barrier();
        asm volatile("s_waitcnt lgkmcnt(0)" ::: "memory");
        __builtin_amdgcn_sched_barrier(0);
        __builtin_amdgcn_s_setprio(1);
#pragma unroll
        for (int m = 0; m < 4; ++m)
#pragma unroll
            for (int n = 0; n < 2; ++n) {
                acc[m][n] = MFMA(a0[m][0], b0[n][0], acc[m][n]);
                acc[m][n] = MFMA(a0[m][1], b0[n][1], acc[m][n]);
            }
        __builtin_amdgcn_s_setprio(0);
        __builtin_amdgcn_s_barrier();
        FENCE();

        // ===== phase 2: read B n2-3 (4); MFMA quadrant 1 =====
#pragma unroll
        for (int n = 0; n < 2; ++n) {
            b1[n][0] = *(const bf16x8*)(sB + rowB + (2 + n) * 1024 + cOff0);
            b1[n][1] = *(const bf16x8*)(sB + rowB + (2 + n) * 1024 + cOff1);
        }
        __builtin_amdgcn_s_barrier();
        asm volatile("s_waitcnt lgkmcnt(0)" ::: "memory");
        __builtin_amdgcn_sched_barrier(0);
        __builtin_amdgcn_s_setprio(1);
#pragma unroll
        for (int m = 0; m < 4; ++m)
#pragma unroll
            for (int n = 0; n < 2; ++n) {
                acc[m][2 + n] = MFMA(a0[m][0], b1[n][0], acc[m][2 + n]);
                acc[m][2 + n] = MFMA(a0[m][1], b1[n][1], acc[m][2 + n]);
            }
        __builtin_amdgcn_s_setprio(0);
        __builtin_amdgcn_s_barrier();
        FENCE();

        // ===== phase 3: read A m4-7 (8); stage B(tk+2) (B-reads retired
        //       at ph2's lgkmcnt, all waves past ph2's closing barrier) ====
#pragma unroll
        for (int m = 0; m < 4; ++m) {
            a1[m][0] = *(const bf16x8*)(sA + rowA + (4 + m) * 1024 + cOff0);
            a1[m][1] = *(const bf16x8*)(sA + rowA + (4 + m) * 1024 + cOff1);
        }
        if (tk + 2 < NT) STAGE_B(q, tk + 2);
        __builtin_amdgcn_s_barrier();
        asm volatile("s_waitcnt lgkmcnt(0)" ::: "memory");
        __builtin_amdgcn_sched_barrier(0);
        __builtin_amdgcn_s_setprio(1);
#pragma unroll
        for (int m = 0; m < 4; ++m)
#pragma unroll
            for (int n = 0; n < 2; ++n) {
                acc[4 + m][n] = MFMA(a1[m][0], b0[n][0], acc[4 + m][n]);
                acc[4 + m][n] = MFMA(a1[m][1], b0[n][1], acc[4 + m][n]);
            }
        __builtin_amdgcn_s_setprio(0);
        __builtin_amdgcn_s_barrier();
        FENCE();

        // ===== phase 4: stage A(tk+2); MFMA quadrant 3; counted drain ====
        if (tk + 2 < NT) STAGE_A(q, tk + 2);
        __builtin_amdgcn_s_barrier();
        __builtin_amdgcn_s_setprio(1);
#pragma unroll
        for (int m = 0; m < 4; ++m)
#pragma unroll
            for (int n = 0; n < 2; ++n) {
                acc[4 + m][2 + n] = MFMA(a1[m][0], b1[n][0], acc[4 + m][2 + n]);
                acc[4 + m][2 + n] = MFMA(a1[m][1], b1[n][1], acc[4 + m][2 + n]);
            }
        __builtin_amdgcn_s_setprio(0);
        // steady state: 16 outstanding (tk+1's 8 oldest + tk+2's 8) ->
        // vmcnt(8) drains exactly tile tk+1 (order pinned by FENCEs).
        if (tk <= NT - 3) asm volatile("s_waitcnt vmcnt(8)" ::: "memory");
        else              asm volatile("s_waitcnt vmcnt(0)" ::: "memory");
        __builtin_amdgcn_sched_barrier(0);
        __builtin_amdgcn_s_barrier();
        FENCE();
    }

#undef STAGE_A
#undef STAGE_B

    // epilogue: C/D layout col = lane&15, row = (lane>>4)*4 + j
    const long cb = blockN + wc * 64;
    float bv[4];
    long  cn[4];
#pragma unroll
    for (int n = 0; n < 4; ++n) {
        cn[n] = cb + n * 16 + l15;
        bv[n] = bias[cn[n]];
    }
#pragma unroll
    for (int m = 0; m < 8; ++m) {
        const long r0 = blockM + wr * 128 + m * 16 + lk * 4;
#pragma unroll
        for (int n = 0; n < 4; ++n)
#pragma unroll
            for (int j = 0; j < 4; ++j)
                C[(r0 + j) * (long)N_DIM + cn[n]] = acc[m][n][j] + bv[n];
    }
}

// ---------------- fp32 fallback (only if ws too small) ---------------------
__global__ void __launch_bounds__(256) gemm_f32_fallback(
    const float* __restrict__ A, const float* __restrict__ W,
    const float* __restrict__ bias, float* __restrict__ C)
{
    __shared__ float sA[64][17];
    __shared__ float sB[64][17];
    const int bm = blockIdx.y, bn = blockIdx.x;
    const int t = threadIdx.x;
    const int tx = t & 15, ty = t >> 4;
    const long row0 = (long)bm * 64, col0 = (long)bn * 64;
    float acc[4][4] = {};
    for (int kt = 0; kt < K_DIM; kt += 16) {
        const int r = t >> 2, c = (t & 3) * 4;
        float4 a4 = *(const float4*)&A[(row0 + r) * K_DIM + kt + c];
        float4 b4 = *(const float4*)&W[(col0 + r) * K_DIM + kt + c];
        sA[r][c] = a4.x; sA[r][c + 1] = a4.y; sA[r][c + 2] = a4.z; sA[r][c + 3] = a4.w;
        sB[r][c] = b4.x; sB[r][c + 1] = b4.y; sB[r][c + 2] = b4.z; sB[r][c + 3] = b4.w;
        __syncthreads();
#pragma unroll
        for (int kk = 0; kk < 16; ++kk) {
            float av[4], bv[4];
#pragma unroll
            for (int i = 0; i < 4; ++i) av[i] = sA[ty * 4 + i][kk];
#pragma unroll
            for (int j = 0; j < 4; ++j) bv[j] = sB[tx * 4 + j][kk];
#pragma unroll
            for (int i = 0; i < 4; ++i)
#pragma unroll
                for (int j = 0; j < 4; ++j) acc[i][j] += av[i] * bv[j];
        }
        __syncthreads();
    }
#pragma unroll
    for (int i = 0; i < 4; ++i)
#pragma unroll
        for (int j = 0; j < 4; ++j)
            C[(row0 + ty * 4 + i) * N_DIM + col0 + tx * 4 + j] =
                acc[i][j] + bias[col0 + tx * 4 + j];
}

extern "C" void kernel_launch(void* const* d_in, const int* in_sizes, int n_in,
                              void* d_out, int out_size, void* d_ws, size_t ws_size,
                              hipStream_t stream)
{
    const float* x = (const float*)d_in[0];   // [8192, 4096]
    const float* W = (const float*)d_in[1];   // [4096, 4096]
    const float* b = (const float*)d_in[2];   // [4096]
    float* out = (float*)d_out;               // [8192, 4096] fp32

    const long xe = (long)M_DIM * K_DIM;
    const long we = (long)N_DIM * K_DIM;
    const size_t need = (size_t)(xe + we) * sizeof(bf16_t);  // ~96 MiB

    if (ws_size >= need) {
        bf16_t* xb = (bf16_t*)d_ws;
        bf16_t* wb = xb + xe;
        cvt_f32_bf16<<<2048, 256, 0, stream>>>(x, xb, xe / 8);
        cvt_f32_bf16<<<1024, 256, 0, stream>>>(W, wb, we / 8);
        gemm_256_8ph<<<(M_DIM / 256) * (N_DIM / 256), 512, 0, stream>>>(xb, wb, b, out);
    } else {
        dim3 grid(N_DIM / 64, M_DIM / 64);
        gemm_f32_fallback<<<grid, 256, 0, stream>>>(x, W, b, out);
    }
}

// Round 5
// 275.362 us; speedup vs baseline: 1.4837x; 1.0772x over previous
//
#include <hip/hip_runtime.h>
#include <hip/hip_bf16.h>
#include <stdint.h>

// EvolvedLoopLinear: out[b,j] = sum_i x[b,i]*W[j,i] + b[j]
// M=8192, N=4096, K=4096. fp32 in/out, bf16 MFMA compute.
// Round 5: full m201-style 8-phase schedule. 256x256 tile, BK=64, 8 waves,
// 128 KiB LDS (2 parity buffers x 4 regions x 8 KiB), region-major LDS
// layout so each stage unit = 1 region = 2 global_load_lds. One stage unit
// per phase; vmcnt(6) at phases 4 and 8 only (derived from WAR/RAW ledger,
// matches m201's constant). T1 XCD swizzle, T2 XOR chunk swizzle (0 bank
// conflicts in round 4), T4 counted vmcnt, T5 setprio. Fence discipline
// validated in round 4 (prologue inter-group fences pin vmcnt counting).

typedef __bf16 bf16_t;
typedef __bf16 bf16x8 __attribute__((ext_vector_type(8)));
typedef float  f32x4  __attribute__((ext_vector_type(4)));

#define M_DIM 8192
#define N_DIM 4096
#define K_DIM 4096
#define NT    (K_DIM / 64)    // 64 K-tiles of BK=64
#define NITER (NT / 2)        // 32 iterations, 2 K-tiles each

#define GLD16(gp, lp) __builtin_amdgcn_global_load_lds(                    \
    (const __attribute__((address_space(1))) void*)(gp),                   \
    (__attribute__((address_space(3))) void*)(lp), 16, 0, 0)

#define MFMA(a, b, c) __builtin_amdgcn_mfma_f32_16x16x32_bf16((a), (b), (c), 0, 0, 0)

#define FENCE() asm volatile("" ::: "memory")

// ---------------- fp32 -> bf16 convert (vectorized, grid-stride) -----------
__global__ void __launch_bounds__(256) cvt_f32_bf16(
    const float* __restrict__ in, bf16_t* __restrict__ out, long n8)
{
    long i0 = (long)blockIdx.x * blockDim.x + threadIdx.x;
    long stride = (long)gridDim.x * blockDim.x;
    for (long i = i0; i < n8; i += stride) {
        const float4* p = (const float4*)(in + i * 8);
        float4 a = p[0];
        float4 b = p[1];
        bf16x8 o;
        o[0] = (bf16_t)a.x; o[1] = (bf16_t)a.y; o[2] = (bf16_t)a.z; o[3] = (bf16_t)a.w;
        o[4] = (bf16_t)b.x; o[5] = (bf16_t)b.y; o[6] = (bf16_t)b.z; o[7] = (bf16_t)b.w;
        *(bf16x8*)(out + i * 8) = o;
    }
}

// ---------------- 256x256 8-phase bf16 GEMM (A,B row-major [*,K]) ----------
// LDS per parity buffer q (32768 el): Am0 @0, Am1 @8192, Bn0 @16384,
// Bn1 @24576. Region rho-rows: Am_h: rho = wr*64 + m*16 + l15 <-> global
// tile row (rho>>6)*128 + h*64 + (rho&63). Bn_h: rho = wc*32 + n*16 + l15
// <-> row (rho>>5)*64 + h*32 + (rho&31). Chunk swizzle within each region:
// slot = chunk ^ (rho&7) (16B granules).
__global__ void __launch_bounds__(512, 1) gemm_256_8ph(
    const bf16_t* __restrict__ A, const bf16_t* __restrict__ B,
    const float* __restrict__ bias, float* __restrict__ C)
{
    __shared__ bf16_t sm[2 * 32768];   // 128 KiB

    // XCD-aware bijective swizzle (gridDim = 512, divisible by 8)
    const int nwg = gridDim.x;
    const int bid = blockIdx.x;
    const int cpx = nwg >> 3;
    const int swz = (bid & 7) * cpx + (bid >> 3);
    const int NBN = N_DIM / 256;                       // 16
    const long blockM = (long)(swz / NBN) * 256;
    const long blockN = (long)(swz % NBN) * 256;

    const int t    = threadIdx.x;
    const int lane = t & 63;
    const int wid  = t >> 6;        // 8 waves: 2 (M) x 4 (N)
    const int wr   = wid >> 2;      // 0..1 -> 128 rows each
    const int wc   = wid & 3;       // 0..3 -> 64 cols each
    const int l15  = lane & 15;
    const int lk   = lane >> 4;     // 0..3

    // staging: LDS dest linear (t*16B within region line); global src row
    // per region mapping, chunk carries inverse swizzle.
    const int cg  = (t & 7) ^ ((t >> 3) & 7);
    const int rA0 = (t >> 3);                                  // A line-0 row
    const int rB0 = ((t >> 3) & 31) | (((t >> 3) & 32) << 1);  // B line-0 row
    const bf16_t* gA = A + (blockM + rA0) * (long)K_DIM + cg * 8;
    const bf16_t* gB = B + (blockN + rB0) * (long)K_DIM + cg * 8;
    const int dstT = t * 8;         // 16 B per thread, linear within line

    // read side: fragment rho&7 == l15&7 for all fragments
    const int swzr = l15 & 7;
    const int cOff0 = ((0 * 4 + lk) ^ swzr) << 3;
    const int cOff1 = ((1 * 4 + lk) ^ swzr) << 3;
    const int aBase = wr * 4096 + l15 * 64;            // within Am region
    const int bBase = 16384 + wc * 2048 + l15 * 64;    // within buffer (Bn0)

    f32x4 acc[8][4] = {};

    // stage one A region h (0=Am0,1=Am1) of tile tk into buffer q
#define STAGE_A(q, tk, h) do {                                             \
    const bf16_t* _g = gA + (long)(tk) * 64 + (long)(h) * 64 * K_DIM;      \
    bf16_t* _l = (bf16_t*)sm + (q) * 32768 + (h) * 8192 + dstT;            \
    GLD16(_g,                _l);                                          \
    GLD16(_g + 128L * K_DIM, _l + 4096); } while (0)

    // stage one B region h (0=Bn0,1=Bn1)
#define STAGE_B(q, tk, h) do {                                             \
    const bf16_t* _g = gB + (long)(tk) * 64 + (long)(h) * 32 * K_DIM;      \
    bf16_t* _l = (bf16_t*)sm + (q) * 32768 + 16384 + (h) * 8192 + dstT;    \
    GLD16(_g,                _l);                                          \
    GLD16(_g + 128L * K_DIM, _l + 4096); } while (0)

    // prologue: tile0 all 4 regions (8 loads) | tile1 minus Am1 (6 loads).
    // Fences pin issue order so vmcnt counting is exact.
    STAGE_A(0, 0, 0); STAGE_A(0, 0, 1); STAGE_B(0, 0, 0); STAGE_B(0, 0, 1);
    FENCE();
    STAGE_A(1, 1, 0); STAGE_B(1, 1, 0); STAGE_B(1, 1, 1);
    FENCE();
    asm volatile("s_waitcnt vmcnt(6)" ::: "memory");   // tile0 landed
    __builtin_amdgcn_sched_barrier(0);
    __builtin_amdgcn_s_barrier();
    FENCE();

    bf16x8 a0[4][2], a1[4][2], b0[2][2], b1[2][2];

    for (int i = 0; i < NITER; ++i) {
        const int tk0 = 2 * i;
        const int tk1 = 2 * i + 1;
        const bool full = (i < NITER - 1);
        const bf16_t* s0 = (const bf16_t*)sm;           // buf0 (even tiles)
        const bf16_t* s1 = (const bf16_t*)sm + 32768;   // buf1 (odd tiles)

        // ========== P1: read Am0,Bn0(b0); stage Am1(tile tk1 -> b1) =======
#pragma unroll
        for (int m = 0; m < 4; ++m) {
            a0[m][0] = *(const bf16x8*)(s0 + aBase + m * 1024 + cOff0);
            a0[m][1] = *(const bf16x8*)(s0 + aBase + m * 1024 + cOff1);
        }
#pragma unroll
        for (int n = 0; n < 2; ++n) {
            b0[n][0] = *(const bf16x8*)(s0 + bBase + n * 1024 + cOff0);
            b0[n][1] = *(const bf16x8*)(s0 + bBase + n * 1024 + cOff1);
        }
        STAGE_A(1, tk1, 1);
        FENCE();
        __builtin_amdgcn_s_barrier();
        asm volatile("s_waitcnt lgkmcnt(0)" ::: "memory");
        __builtin_amdgcn_sched_barrier(0);
        __builtin_amdgcn_s_setprio(1);
#pragma unroll
        for (int m = 0; m < 4; ++m)
#pragma unroll
            for (int n = 0; n < 2; ++n) {
                acc[m][n] = MFMA(a0[m][0], b0[n][0], acc[m][n]);
                acc[m][n] = MFMA(a0[m][1], b0[n][1], acc[m][n]);
            }
        __builtin_amdgcn_s_setprio(0);
        __builtin_amdgcn_s_barrier();
        FENCE();

        // ========== P2: read Bn1(b0); stage Am0(tk0+2 -> b0) ==============
#pragma unroll
        for (int n = 0; n < 2; ++n) {
            b1[n][0] = *(const bf16x8*)(s0 + bBase + 8192 + n * 1024 + cOff0);
            b1[n][1] = *(const bf16x8*)(s0 + bBase + 8192 + n * 1024 + cOff1);
        }
        if (full) STAGE_A(0, tk0 + 2, 0);
        FENCE();
        __builtin_amdgcn_s_barrier();
        asm volatile("s_waitcnt lgkmcnt(0)" ::: "memory");
        __builtin_amdgcn_sched_barrier(0);
        __builtin_amdgcn_s_setprio(1);
#pragma unroll
        for (int m = 0; m < 4; ++m)
#pragma unroll
            for (int n = 0; n < 2; ++n) {
                acc[m][2 + n] = MFMA(a0[m][0], b1[n][0], acc[m][2 + n]);
                acc[m][2 + n] = MFMA(a0[m][1], b1[n][1], acc[m][2 + n]);
            }
        __builtin_amdgcn_s_setprio(0);
        __builtin_amdgcn_s_barrier();
        FENCE();

        // ========== P3: read Am1(b0); stage Bn0(tk0+2 -> b0) ==============
#pragma unroll
        for (int m = 0; m < 4; ++m) {
            a1[m][0] = *(const bf16x8*)(s0 + 8192 + aBase + m * 1024 + cOff0);
            a1[m][1] = *(const bf16x8*)(s0 + 8192 + aBase + m * 1024 + cOff1);
        }
        if (full) STAGE_B(0, tk0 + 2, 0);
        FENCE();
        __builtin_amdgcn_s_barrier();
        asm volatile("s_waitcnt lgkmcnt(0)" ::: "memory");
        __builtin_amdgcn_sched_barrier(0);
        __builtin_amdgcn_s_setprio(1);
#pragma unroll
        for (int m = 0; m < 4; ++m)
#pragma unroll
            for (int n = 0; n < 2; ++n) {
                acc[4 + m][n] = MFMA(a1[m][0], b0[n][0], acc[4 + m][n]);
                acc[4 + m][n] = MFMA(a1[m][1], b0[n][1], acc[4 + m][n]);
            }
        __builtin_amdgcn_s_setprio(0);
        __builtin_amdgcn_s_barrier();
        FENCE();

        // ========== P4: stage Bn1(tk0+2 -> b0); MFMA q3; vmcnt(6) =========
        if (full) STAGE_B(0, tk0 + 2, 1);
        FENCE();
        __builtin_amdgcn_s_barrier();
        __builtin_amdgcn_s_setprio(1);
#pragma unroll
        for (int m = 0; m < 4; ++m)
#pragma unroll
            for (int n = 0; n < 2; ++n) {
                acc[4 + m][2 + n] = MFMA(a1[m][0], b1[n][0], acc[4 + m][2 + n]);
                acc[4 + m][2 + n] = MFMA(a1[m][1], b1[n][1], acc[4 + m][2 + n]);
            }
        __builtin_amdgcn_s_setprio(0);
        if (full) asm volatile("s_waitcnt vmcnt(6)" ::: "memory");
        else      asm volatile("s_waitcnt vmcnt(0)" ::: "memory");
        __builtin_amdgcn_sched_barrier(0);
        __builtin_amdgcn_s_barrier();
        FENCE();

        // ========== P5: read Am0,Bn0(b1); stage Am1(tk0+2 -> b0) ==========
#pragma unroll
        for (int m = 0; m < 4; ++m) {
            a0[m][0] = *(const bf16x8*)(s1 + aBase + m * 1024 + cOff0);
            a0[m][1] = *(const bf16x8*)(s1 + aBase + m * 1024 + cOff1);
        }
#pragma unroll
        for (int n = 0; n < 2; ++n) {
            b0[n][0] = *(const bf16x8*)(s1 + bBase + n * 1024 + cOff0);
            b0[n][1] = *(const bf16x8*)(s1 + bBase + n * 1024 + cOff1);
        }
        if (full) STAGE_A(0, tk0 + 2, 1);
        FENCE();
        __builtin_amdgcn_s_barrier();
        asm volatile("s_waitcnt lgkmcnt(0)" ::: "memory");
        __builtin_amdgcn_sched_barrier(0);
        __builtin_amdgcn_s_setprio(1);
#pragma unroll
        for (int m = 0; m < 4; ++m)
#pragma unroll
            for (int n = 0; n < 2; ++n) {
                acc[m][n] = MFMA(a0[m][0], b0[n][0], acc[m][n]);
                acc[m][n] = MFMA(a0[m][1], b0[n][1], acc[m][n]);
            }
        __builtin_amdgcn_s_setprio(0);
        __builtin_amdgcn_s_barrier();
        FENCE();

        // ========== P6: read Bn1(b1); stage Am0(tk1+2 -> b1) ==============
#pragma unroll
        for (int n = 0; n < 2; ++n) {
            b1[n][0] = *(const bf16x8*)(s1 + bBase + 8192 + n * 1024 + cOff0);
            b1[n][1] = *(const bf16x8*)(s1 + bBase + 8192 + n * 1024 + cOff1);
        }
        if (full) STAGE_A(1, tk1 + 2, 0);
        FENCE();
        __builtin_amdgcn_s_barrier();
        asm volatile("s_waitcnt lgkmcnt(0)" ::: "memory");
        __builtin_amdgcn_sched_barrier(0);
        __builtin_amdgcn_s_setprio(1);
#pragma unroll
        for (int m = 0; m < 4; ++m)
#pragma unroll
            for (int n = 0; n < 2; ++n) {
                acc[m][2 + n] = MFMA(a0[m][0], b1[n][0], acc[m][2 + n]);
                acc[m][2 + n] = MFMA(a0[m][1], b1[n][1], acc[m][2 + n]);
            }
        __builtin_amdgcn_s_setprio(0);
        __builtin_amdgcn_s_barrier();
        FENCE();

        // ========== P7: read Am1(b1); stage Bn0(tk1+2 -> b1) ==============
#pragma unroll
        for (int m = 0; m < 4; ++m) {
            a1[m][0] = *(const bf16x8*)(s1 + 8192 + aBase + m * 1024 + cOff0);
            a1[m][1] = *(const bf16x8*)(s1 + 8192 + aBase + m * 1024 + cOff1);
        }
        if (full) STAGE_B(1, tk1 + 2, 0);
        FENCE();
        __builtin_amdgcn_s_barrier();
        asm volatile("s_waitcnt lgkmcnt(0)" ::: "memory");
        __builtin_amdgcn_sched_barrier(0);
        __builtin_amdgcn_s_setprio(1);
#pragma unroll
        for (int m = 0; m < 4; ++m)
#pragma unroll
            for (int n = 0; n < 2; ++n) {
                acc[4 + m][n] = MFMA(a1[m][0], b0[n][0], acc[4 + m][n]);
                acc[4 + m][n] = MFMA(a1[m][1], b0[n][1], acc[4 + m][n]);
            }
        __builtin_amdgcn_s_setprio(0);
        __builtin_amdgcn_s_barrier();
        FENCE();

        // ========== P8: stage Bn1(tk1+2 -> b1); MFMA q3; vmcnt(6) =========
        if (full) STAGE_B(1, tk1 + 2, 1);
        FENCE();
        __builtin_amdgcn_s_barrier();
        __builtin_amdgcn_s_setprio(1);
#pragma unroll
        for (int m = 0; m < 4; ++m)
#pragma unroll
            for (int n = 0; n < 2; ++n) {
                acc[4 + m][2 + n] = MFMA(a1[m][0], b1[n][0], acc[4 + m][2 + n]);
                acc[4 + m][2 + n] = MFMA(a1[m][1], b1[n][1], acc[4 + m][2 + n]);
            }
        __builtin_amdgcn_s_setprio(0);
        if (full) asm volatile("s_waitcnt vmcnt(6)" ::: "memory");
        else      asm volatile("s_waitcnt vmcnt(0)" ::: "memory");
        __builtin_amdgcn_sched_barrier(0);
        __builtin_amdgcn_s_barrier();
        FENCE();
    }

#undef STAGE_A
#undef STAGE_B

    // epilogue: C/D layout col = lane&15, row = (lane>>4)*4 + j
    const long cb = blockN + wc * 64;
    float bv[4];
    long  cn[4];
#pragma unroll
    for (int n = 0; n < 4; ++n) {
        cn[n] = cb + n * 16 + l15;
        bv[n] = bias[cn[n]];
    }
#pragma unroll
    for (int m = 0; m < 8; ++m) {
        const long r0 = blockM + wr * 128 + m * 16 + lk * 4;
#pragma unroll
        for (int n = 0; n < 4; ++n)
#pragma unroll
            for (int j = 0; j < 4; ++j)
                C[(r0 + j) * (long)N_DIM + cn[n]] = acc[m][n][j] + bv[n];
    }
}

// ---------------- fp32 fallback (only if ws too small) ---------------------
__global__ void __launch_bounds__(256) gemm_f32_fallback(
    const float* __restrict__ A, const float* __restrict__ W,
    const float* __restrict__ bias, float* __restrict__ C)
{
    __shared__ float sA[64][17];
    __shared__ float sB[64][17];
    const int bm = blockIdx.y, bn = blockIdx.x;
    const int t = threadIdx.x;
    const int tx = t & 15, ty = t >> 4;
    const long row0 = (long)bm * 64, col0 = (long)bn * 64;
    float acc[4][4] = {};
    for (int kt = 0; kt < K_DIM; kt += 16) {
        const int r = t >> 2, c = (t & 3) * 4;
        float4 a4 = *(const float4*)&A[(row0 + r) * K_DIM + kt + c];
        float4 b4 = *(const float4*)&W[(col0 + r) * K_DIM + kt + c];
        sA[r][c] = a4.x; sA[r][c + 1] = a4.y; sA[r][c + 2] = a4.z; sA[r][c + 3] = a4.w;
        sB[r][c] = b4.x; sB[r][c + 1] = b4.y; sB[r][c + 2] = b4.z; sB[r][c + 3] = b4.w;
        __syncthreads();
#pragma unroll
        for (int kk = 0; kk < 16; ++kk) {
            float av[4], bv[4];
#pragma unroll
            for (int i = 0; i < 4; ++i) av[i] = sA[ty * 4 + i][kk];
#pragma unroll
            for (int j = 0; j < 4; ++j) bv[j] = sB[tx * 4 + j][kk];
#pragma unroll
            for (int i = 0; i < 4; ++i)
#pragma unroll
                for (int j = 0; j < 4; ++j) acc[i][j] += av[i] * bv[j];
        }
        __syncthreads();
    }
#pragma unroll
    for (int i = 0; i < 4; ++i)
#pragma unroll
        for (int j = 0; j < 4; ++j)
            C[(row0 + ty * 4 + i) * N_DIM + col0 + tx * 4 + j] =
                acc[i][j] + bias[col0 + tx * 4 + j];
}

extern "C" void kernel_launch(void* const* d_in, const int* in_sizes, int n_in,
                              void* d_out, int out_size, void* d_ws, size_t ws_size,
                              hipStream_t stream)
{
    const float* x = (const float*)d_in[0];   // [8192, 4096]
    const float* W = (const float*)d_in[1];   // [4096, 4096]
    const float* b = (const float*)d_in[2];   // [4096]
    float* out = (float*)d_out;               // [8192, 4096] fp32

    const long xe = (long)M_DIM * K_DIM;
    const long we = (long)N_DIM * K_DIM;
    const size_t need = (size_t)(xe + we) * sizeof(bf16_t);  // ~96 MiB

    if (ws_size >= need) {
        bf16_t* xb = (bf16_t*)d_ws;
        bf16_t* wb = xb + xe;
        cvt_f32_bf16<<<2048, 256, 0, stream>>>(x, xb, xe / 8);
        cvt_f32_bf16<<<1024, 256, 0, stream>>>(W, wb, we / 8);
        gemm_256_8ph<<<(M_DIM / 256) * (N_DIM / 256), 512, 0, stream>>>(xb, wb, b, out);
    } else {
        dim3 grid(N_DIM / 64, M_DIM / 64);
        gemm_f32_fallback<<<grid, 256, 0, stream>>>(x, W, b, out);
    }
}

// Round 6
// 267.762 us; speedup vs baseline: 1.5258x; 1.0284x over previous
//
#include <hip/hip_runtime.h>
#include <hip/hip_bf16.h>
#include <stdint.h>

// EvolvedLoopLinear: out[b,j] = sum_i x[b,i]*W[j,i] + b[j]
// M=8192, N=4096, K=4096. fp32 in/out, bf16 MFMA compute.
// Round 6: ONE barrier per phase (mid-phase barrier removed — WAR gated by
// end-of-phase barrier, RAW by per-wave vmcnt(6)+barrier at P4/P8). Waves
// drift <=1 phase -> ds_read window of wave B overlaps MFMA window of wave
// A (the LDS/MFMA overlap the lockstep structure was missing). MFMA loops
// kk-outer (dep distance 8). Everything else = round 5 (256x256, BK=64,
// 8 waves, 128 KiB LDS region-major, XOR chunk swizzle (0 conflicts),
// XCD swizzle, counted vmcnt(6), setprio, fence discipline).

typedef __bf16 bf16_t;
typedef __bf16 bf16x8 __attribute__((ext_vector_type(8)));
typedef float  f32x4  __attribute__((ext_vector_type(4)));

#define M_DIM 8192
#define N_DIM 4096
#define K_DIM 4096
#define NT    (K_DIM / 64)    // 64 K-tiles of BK=64
#define NITER (NT / 2)        // 32 iterations, 2 K-tiles each

#define GLD16(gp, lp) __builtin_amdgcn_global_load_lds(                    \
    (const __attribute__((address_space(1))) void*)(gp),                   \
    (__attribute__((address_space(3))) void*)(lp), 16, 0, 0)

#define MFMA(a, b, c) __builtin_amdgcn_mfma_f32_16x16x32_bf16((a), (b), (c), 0, 0, 0)

#define FENCE() asm volatile("" ::: "memory")

// ---------------- fp32 -> bf16 convert (vectorized, grid-stride) -----------
__global__ void __launch_bounds__(256) cvt_f32_bf16(
    const float* __restrict__ in, bf16_t* __restrict__ out, long n8)
{
    long i0 = (long)blockIdx.x * blockDim.x + threadIdx.x;
    long stride = (long)gridDim.x * blockDim.x;
    for (long i = i0; i < n8; i += stride) {
        const float4* p = (const float4*)(in + i * 8);
        float4 a = p[0];
        float4 b = p[1];
        bf16x8 o;
        o[0] = (bf16_t)a.x; o[1] = (bf16_t)a.y; o[2] = (bf16_t)a.z; o[3] = (bf16_t)a.w;
        o[4] = (bf16_t)b.x; o[5] = (bf16_t)b.y; o[6] = (bf16_t)b.z; o[7] = (bf16_t)b.w;
        *(bf16x8*)(out + i * 8) = o;
    }
}

// ---------------- 256x256 8-phase bf16 GEMM (A,B row-major [*,K]) ----------
// LDS per parity buffer q (32768 el): Am0 @0, Am1 @8192, Bn0 @16384,
// Bn1 @24576. Chunk swizzle within each region: slot = chunk ^ (rho&7).
__global__ void __launch_bounds__(512, 1) gemm_256_8ph(
    const bf16_t* __restrict__ A, const bf16_t* __restrict__ B,
    const float* __restrict__ bias, float* __restrict__ C)
{
    __shared__ bf16_t sm[2 * 32768];   // 128 KiB

    // XCD-aware bijective swizzle (gridDim = 512, divisible by 8)
    const int nwg = gridDim.x;
    const int bid = blockIdx.x;
    const int cpx = nwg >> 3;
    const int swz = (bid & 7) * cpx + (bid >> 3);
    const int NBN = N_DIM / 256;                       // 16
    const long blockM = (long)(swz / NBN) * 256;
    const long blockN = (long)(swz % NBN) * 256;

    const int t    = threadIdx.x;
    const int lane = t & 63;
    const int wid  = t >> 6;        // 8 waves: 2 (M) x 4 (N)
    const int wr   = wid >> 2;      // 0..1 -> 128 rows each
    const int wc   = wid & 3;       // 0..3 -> 64 cols each
    const int l15  = lane & 15;
    const int lk   = lane >> 4;     // 0..3

    // staging: LDS dest linear (t*16B within region line); global src row
    // per region mapping, chunk carries inverse swizzle.
    const int cg  = (t & 7) ^ ((t >> 3) & 7);
    const int rA0 = (t >> 3);                                  // A line-0 row
    const int rB0 = ((t >> 3) & 31) | (((t >> 3) & 32) << 1);  // B line-0 row
    const bf16_t* gA = A + (blockM + rA0) * (long)K_DIM + cg * 8;
    const bf16_t* gB = B + (blockN + rB0) * (long)K_DIM + cg * 8;
    const int dstT = t * 8;         // 16 B per thread, linear within line

    // read side: fragment rho&7 == l15&7 for all fragments
    const int swzr = l15 & 7;
    const int cOff0 = ((0 * 4 + lk) ^ swzr) << 3;
    const int cOff1 = ((1 * 4 + lk) ^ swzr) << 3;
    const int aBase = wr * 4096 + l15 * 64;            // within Am region
    const int bBase = 16384 + wc * 2048 + l15 * 64;    // within buffer (Bn0)

    f32x4 acc[8][4] = {};

#define STAGE_A(q, tk, h) do {                                             \
    const bf16_t* _g = gA + (long)(tk) * 64 + (long)(h) * 64 * K_DIM;      \
    bf16_t* _l = (bf16_t*)sm + (q) * 32768 + (h) * 8192 + dstT;            \
    GLD16(_g,                _l);                                          \
    GLD16(_g + 128L * K_DIM, _l + 4096); } while (0)

#define STAGE_B(q, tk, h) do {                                             \
    const bf16_t* _g = gB + (long)(tk) * 64 + (long)(h) * 32 * K_DIM;      \
    bf16_t* _l = (bf16_t*)sm + (q) * 32768 + 16384 + (h) * 8192 + dstT;    \
    GLD16(_g,                _l);                                          \
    GLD16(_g + 128L * K_DIM, _l + 4096); } while (0)

    // phase close-out: per-wave DS drain, pinned MFMA cluster, one barrier.
#define LGKM_SB()                                                          \
    asm volatile("s_waitcnt lgkmcnt(0)" ::: "memory");                     \
    __builtin_amdgcn_sched_barrier(0)

#define END_BARRIER()                                                      \
    __builtin_amdgcn_s_barrier();                                          \
    FENCE()

    // prologue: tile0 all 4 regions (8 loads) | tile1 minus Am1 (6 loads).
    STAGE_A(0, 0, 0); STAGE_A(0, 0, 1); STAGE_B(0, 0, 0); STAGE_B(0, 0, 1);
    FENCE();
    STAGE_A(1, 1, 0); STAGE_B(1, 1, 0); STAGE_B(1, 1, 1);
    FENCE();
    asm volatile("s_waitcnt vmcnt(6)" ::: "memory");   // tile0 landed
    __builtin_amdgcn_sched_barrier(0);
    END_BARRIER();

    bf16x8 a0[4][2], a1[4][2], b0[2][2], b1[2][2];

    for (int i = 0; i < NITER; ++i) {
        const int tk0 = 2 * i;
        const int tk1 = 2 * i + 1;
        const bool full = (i < NITER - 1);
        const bf16_t* s0 = (const bf16_t*)sm;           // buf0 (even tiles)
        const bf16_t* s1 = (const bf16_t*)sm + 32768;   // buf1 (odd tiles)

        // ========== P1: read Am0,Bn0(b0); stage Am1(b1,tk1); MFMA q0 ======
#pragma unroll
        for (int m = 0; m < 4; ++m) {
            a0[m][0] = *(const bf16x8*)(s0 + aBase + m * 1024 + cOff0);
            a0[m][1] = *(const bf16x8*)(s0 + aBase + m * 1024 + cOff1);
        }
#pragma unroll
        for (int n = 0; n < 2; ++n) {
            b0[n][0] = *(const bf16x8*)(s0 + bBase + n * 1024 + cOff0);
            b0[n][1] = *(const bf16x8*)(s0 + bBase + n * 1024 + cOff1);
        }
        STAGE_A(1, tk1, 1);
        FENCE();
        LGKM_SB();
        __builtin_amdgcn_s_setprio(1);
#pragma unroll
        for (int kk = 0; kk < 2; ++kk)
#pragma unroll
            for (int m = 0; m < 4; ++m)
#pragma unroll
                for (int n = 0; n < 2; ++n)
                    acc[m][n] = MFMA(a0[m][kk], b0[n][kk], acc[m][n]);
        __builtin_amdgcn_s_setprio(0);
        END_BARRIER();

        // ========== P2: read Bn1(b0); stage Am0(b0,tk0+2); MFMA q1 ========
#pragma unroll
        for (int n = 0; n < 2; ++n) {
            b1[n][0] = *(const bf16x8*)(s0 + bBase + 8192 + n * 1024 + cOff0);
            b1[n][1] = *(const bf16x8*)(s0 + bBase + 8192 + n * 1024 + cOff1);
        }
        if (full) STAGE_A(0, tk0 + 2, 0);
        FENCE();
        LGKM_SB();
        __builtin_amdgcn_s_setprio(1);
#pragma unroll
        for (int kk = 0; kk < 2; ++kk)
#pragma unroll
            for (int m = 0; m < 4; ++m)
#pragma unroll
                for (int n = 0; n < 2; ++n)
                    acc[m][2 + n] = MFMA(a0[m][kk], b1[n][kk], acc[m][2 + n]);
        __builtin_amdgcn_s_setprio(0);
        END_BARRIER();

        // ========== P3: read Am1(b0); stage Bn0(b0,tk0+2); MFMA q2 ========
#pragma unroll
        for (int m = 0; m < 4; ++m) {
            a1[m][0] = *(const bf16x8*)(s0 + 8192 + aBase + m * 1024 + cOff0);
            a1[m][1] = *(const bf16x8*)(s0 + 8192 + aBase + m * 1024 + cOff1);
        }
        if (full) STAGE_B(0, tk0 + 2, 0);
        FENCE();
        LGKM_SB();
        __builtin_amdgcn_s_setprio(1);
#pragma unroll
        for (int kk = 0; kk < 2; ++kk)
#pragma unroll
            for (int m = 0; m < 4; ++m)
#pragma unroll
                for (int n = 0; n < 2; ++n)
                    acc[4 + m][n] = MFMA(a1[m][kk], b0[n][kk], acc[4 + m][n]);
        __builtin_amdgcn_s_setprio(0);
        END_BARRIER();

        // ========== P4: stage Bn1(b0,tk0+2); MFMA q3; vmcnt(6) ============
        if (full) STAGE_B(0, tk0 + 2, 1);
        FENCE();
        __builtin_amdgcn_s_setprio(1);
#pragma unroll
        for (int kk = 0; kk < 2; ++kk)
#pragma unroll
            for (int m = 0; m < 4; ++m)
#pragma unroll
                for (int n = 0; n < 2; ++n)
                    acc[4 + m][2 + n] = MFMA(a1[m][kk], b1[n][kk], acc[4 + m][2 + n]);
        __builtin_amdgcn_s_setprio(0);
        if (full) asm volatile("s_waitcnt vmcnt(6)" ::: "memory");
        else      asm volatile("s_waitcnt vmcnt(0)" ::: "memory");
        __builtin_amdgcn_sched_barrier(0);
        END_BARRIER();

        // ========== P5: read Am0,Bn0(b1); stage Am1(b0,tk0+2); MFMA q0 ====
#pragma unroll
        for (int m = 0; m < 4; ++m) {
            a0[m][0] = *(const bf16x8*)(s1 + aBase + m * 1024 + cOff0);
            a0[m][1] = *(const bf16x8*)(s1 + aBase + m * 1024 + cOff1);
        }
#pragma unroll
        for (int n = 0; n < 2; ++n) {
            b0[n][0] = *(const bf16x8*)(s1 + bBase + n * 1024 + cOff0);
            b0[n][1] = *(const bf16x8*)(s1 + bBase + n * 1024 + cOff1);
        }
        if (full) STAGE_A(0, tk0 + 2, 1);
        FENCE();
        LGKM_SB();
        __builtin_amdgcn_s_setprio(1);
#pragma unroll
        for (int kk = 0; kk < 2; ++kk)
#pragma unroll
            for (int m = 0; m < 4; ++m)
#pragma unroll
                for (int n = 0; n < 2; ++n)
                    acc[m][n] = MFMA(a0[m][kk], b0[n][kk], acc[m][n]);
        __builtin_amdgcn_s_setprio(0);
        END_BARRIER();

        // ========== P6: read Bn1(b1); stage Am0(b1,tk1+2); MFMA q1 ========
#pragma unroll
        for (int n = 0; n < 2; ++n) {
            b1[n][0] = *(const bf16x8*)(s1 + bBase + 8192 + n * 1024 + cOff0);
            b1[n][1] = *(const bf16x8*)(s1 + bBase + 8192 + n * 1024 + cOff1);
        }
        if (full) STAGE_A(1, tk1 + 2, 0);
        FENCE();
        LGKM_SB();
        __builtin_amdgcn_s_setprio(1);
#pragma unroll
        for (int kk = 0; kk < 2; ++kk)
#pragma unroll
            for (int m = 0; m < 4; ++m)
#pragma unroll
                for (int n = 0; n < 2; ++n)
                    acc[m][2 + n] = MFMA(a0[m][kk], b1[n][kk], acc[m][2 + n]);
        __builtin_amdgcn_s_setprio(0);
        END_BARRIER();

        // ========== P7: read Am1(b1); stage Bn0(b1,tk1+2); MFMA q2 ========
#pragma unroll
        for (int m = 0; m < 4; ++m) {
            a1[m][0] = *(const bf16x8*)(s1 + 8192 + aBase + m * 1024 + cOff0);
            a1[m][1] = *(const bf16x8*)(s1 + 8192 + aBase + m * 1024 + cOff1);
        }
        if (full) STAGE_B(1, tk1 + 2, 0);
        FENCE();
        LGKM_SB();
        __builtin_amdgcn_s_setprio(1);
#pragma unroll
        for (int kk = 0; kk < 2; ++kk)
#pragma unroll
            for (int m = 0; m < 4; ++m)
#pragma unroll
                for (int n = 0; n < 2; ++n)
                    acc[4 + m][n] = MFMA(a1[m][kk], b0[n][kk], acc[4 + m][n]);
        __builtin_amdgcn_s_setprio(0);
        END_BARRIER();

        // ========== P8: stage Bn1(b1,tk1+2); MFMA q3; vmcnt(6) ============
        if (full) STAGE_B(1, tk1 + 2, 1);
        FENCE();
        __builtin_amdgcn_s_setprio(1);
#pragma unroll
        for (int kk = 0; kk < 2; ++kk)
#pragma unroll
            for (int m = 0; m < 4; ++m)
#pragma unroll
                for (int n = 0; n < 2; ++n)
                    acc[4 + m][2 + n] = MFMA(a1[m][kk], b1[n][kk], acc[4 + m][2 + n]);
        __builtin_amdgcn_s_setprio(0);
        if (full) asm volatile("s_waitcnt vmcnt(6)" ::: "memory");
        else      asm volatile("s_waitcnt vmcnt(0)" ::: "memory");
        __builtin_amdgcn_sched_barrier(0);
        END_BARRIER();
    }

#undef STAGE_A
#undef STAGE_B

    // epilogue: C/D layout col = lane&15, row = (lane>>4)*4 + j
    const long cb = blockN + wc * 64;
    float bv[4];
    long  cn[4];
#pragma unroll
    for (int n = 0; n < 4; ++n) {
        cn[n] = cb + n * 16 + l15;
        bv[n] = bias[cn[n]];
    }
#pragma unroll
    for (int m = 0; m < 8; ++m) {
        const long r0 = blockM + wr * 128 + m * 16 + lk * 4;
#pragma unroll
        for (int n = 0; n < 4; ++n)
#pragma unroll
            for (int j = 0; j < 4; ++j)
                C[(r0 + j) * (long)N_DIM + cn[n]] = acc[m][n][j] + bv[n];
    }
}

// ---------------- fp32 fallback (only if ws too small) ---------------------
__global__ void __launch_bounds__(256) gemm_f32_fallback(
    const float* __restrict__ A, const float* __restrict__ W,
    const float* __restrict__ bias, float* __restrict__ C)
{
    __shared__ float sA[64][17];
    __shared__ float sB[64][17];
    const int bm = blockIdx.y, bn = blockIdx.x;
    const int t = threadIdx.x;
    const int tx = t & 15, ty = t >> 4;
    const long row0 = (long)bm * 64, col0 = (long)bn * 64;
    float acc[4][4] = {};
    for (int kt = 0; kt < K_DIM; kt += 16) {
        const int r = t >> 2, c = (t & 3) * 4;
        float4 a4 = *(const float4*)&A[(row0 + r) * K_DIM + kt + c];
        float4 b4 = *(const float4*)&W[(col0 + r) * K_DIM + kt + c];
        sA[r][c] = a4.x; sA[r][c + 1] = a4.y; sA[r][c + 2] = a4.z; sA[r][c + 3] = a4.w;
        sB[r][c] = b4.x; sB[r][c + 1] = b4.y; sB[r][c + 2] = b4.z; sB[r][c + 3] = b4.w;
        __syncthreads();
#pragma unroll
        for (int kk = 0; kk < 16; ++kk) {
            float av[4], bv[4];
#pragma unroll
            for (int i = 0; i < 4; ++i) av[i] = sA[ty * 4 + i][kk];
#pragma unroll
            for (int j = 0; j < 4; ++j) bv[j] = sB[tx * 4 + j][kk];
#pragma unroll
            for (int i = 0; i < 4; ++i)
#pragma unroll
                for (int j = 0; j < 4; ++j) acc[i][j] += av[i] * bv[j];
        }
        __syncthreads();
    }
#pragma unroll
    for (int i = 0; i < 4; ++i)
#pragma unroll
        for (int j = 0; j < 4; ++j)
            C[(row0 + ty * 4 + i) * N_DIM + col0 + tx * 4 + j] =
                acc[i][j] + bias[col0 + tx * 4 + j];
}

extern "C" void kernel_launch(void* const* d_in, const int* in_sizes, int n_in,
                              void* d_out, int out_size, void* d_ws, size_t ws_size,
                              hipStream_t stream)
{
    const float* x = (const float*)d_in[0];   // [8192, 4096]
    const float* W = (const float*)d_in[1];   // [4096, 4096]
    const float* b = (const float*)d_in[2];   // [4096]
    float* out = (float*)d_out;               // [8192, 4096] fp32

    const long xe = (long)M_DIM * K_DIM;
    const long we = (long)N_DIM * K_DIM;
    const size_t need = (size_t)(xe + we) * sizeof(bf16_t);  // ~96 MiB

    if (ws_size >= need) {
        bf16_t* xb = (bf16_t*)d_ws;
        bf16_t* wb = xb + xe;
        cvt_f32_bf16<<<2048, 256, 0, stream>>>(x, xb, xe / 8);
        cvt_f32_bf16<<<1024, 256, 0, stream>>>(W, wb, we / 8);
        gemm_256_8ph<<<(M_DIM / 256) * (N_DIM / 256), 512, 0, stream>>>(xb, wb, b, out);
    } else {
        dim3 grid(N_DIM / 64, M_DIM / 64);
        gemm_f32_fallback<<<grid, 256, 0, stream>>>(x, W, b, out);
    }
}